// Round 1
// baseline (253.059 us; speedup 1.0000x reference)
//
#include <hip/hip_runtime.h>
#include <hip/hip_bf16.h>

// EdgeEncoder — fp32 inputs, algebraically folded attention:
//   k[i,j] = kbase[j] + W2k @ hid[i,j],   W2k = Wk @ W2
//   score  = q.kbase[j] + qw[i,hd].hid[i,j]
//   ctx    = sum_j attn*vbase[j] + W2v @ (sum_j attn*hid[i,j])
//
// R8: attack the latency bound (VALUBusy 42%, Occ 18.9%, HBM 5%).
//  (a) Q=2 queries/wave (was 4): grid 1024, LDS 35.8KB/block -> 4 blocks/CU,
//      4 waves/SIMD (was 2) — doubles latency hiding; total waves 2048->4096.
//  (b) Wq/out_w/proj_w read directly as fp32 float4 from inputs: removes
//      ~4K bf16-unpack instrs/lane (~29% of dynamic VALU) and the whole
//      weight-packing stage of ee_setup. KBt/VB stay bf16 (proven layout).
//
// ws layout (bytes):
//   [0,32K)     W2KT fp32 [e][ch]
//   [32K,64K)   W2VT fp32 [e][ch]
//   [64K,+2M)   KBt  u32  [s][cw][j]  kbase bf16-pairs, j fastest
//   [+2M,+4M)   VB   u32  [s][j][cw]  vbase, cw fastest

typedef unsigned int u32;
#define SCALE 0.17677669529663689f   // 1/sqrt(32)

__device__ __forceinline__ float bl(u32 u){ union{u32 x; float f;} c; c.x = u << 16; return c.f; }
__device__ __forceinline__ float bh(u32 u){ union{u32 x; float f;} c; c.x = u & 0xffff0000u; return c.f; }
__device__ __forceinline__ u32 pk(float a, float b){
  union{float f; u32 x;} ca, cb; ca.f = a; cb.f = b;
  u32 ua = (ca.x + 0x7fffu + ((ca.x >> 16) & 1u)) >> 16;   // RNE fp32->bf16
  u32 ub = (cb.x + 0x7fffu + ((cb.x >> 16) & 1u)) >> 16;
  return ua | (ub << 16);
}
__device__ __forceinline__ float dot8f(float4 w0, float4 w1, float4 f0, float4 f1, float acc){
  acc = fmaf(w0.x, f0.x, acc); acc = fmaf(w0.y, f0.y, acc);
  acc = fmaf(w0.z, f0.z, acc); acc = fmaf(w0.w, f0.w, acc);
  acc = fmaf(w1.x, f1.x, acc); acc = fmaf(w1.y, f1.y, acc);
  acc = fmaf(w1.z, f1.z, acc); acc = fmaf(w1.w, f1.w, acc);
  return acc;
}
__device__ __forceinline__ void wsync(){
  __builtin_amdgcn_s_waitcnt(0xC07F);   // lgkmcnt(0)
  __builtin_amdgcn_wave_barrier();
}

// ---------------- kernel 1: setup (R5-proven, weight-pack stage removed) ----
__global__ __launch_bounds__(256, 2) void ee_setup(
    const float* __restrict__ nf, const float* __restrict__ b2,
    const float* __restrict__ ipw, const float* __restrict__ ipb,
    const float* __restrict__ w2,
    float* __restrict__ W2KT, float* __restrict__ W2VT,
    u32* __restrict__ KBt, u32* __restrict__ VB)
{
  const int tid = threadIdx.x, b = blockIdx.x;
  const int cg = tid >> 6, l = tid & 63;

  if (b >= 512) {              // ---- W2 folds: W2x[ch][e] = Wk/Wv @ W2 ----
    int t = (b - 512) * 4 + cg;
    int kv = t & 1, e = t >> 1;
    int c0 = 2 * l;
    const float4* rp = (const float4*)ipw + (size_t)(128 + kv * 128 + c0) * 32;
    const float* w2e = w2 + __builtin_amdgcn_readfirstlane(e);
    float a0 = 0.f, a1 = 0.f;
    #pragma unroll 8
    for (int c4 = 0; c4 < 32; ++c4) {
      float4 wa = rp[c4], wb = rp[32 + c4];
      float x0 = w2e[(4 * c4 + 0) * 64];
      float x1 = w2e[(4 * c4 + 1) * 64];
      float x2 = w2e[(4 * c4 + 2) * 64];
      float x3 = w2e[(4 * c4 + 3) * 64];
      a0 = fmaf(wa.x, x0, a0); a0 = fmaf(wa.y, x1, a0);
      a0 = fmaf(wa.z, x2, a0); a0 = fmaf(wa.w, x3, a0);
      a1 = fmaf(wb.x, x0, a1); a1 = fmaf(wb.y, x1, a1);
      a1 = fmaf(wb.z, x2, a1); a1 = fmaf(wb.w, x3, a1);
    }
    float* dst = kv ? W2VT : W2KT;
    ((float2*)dst)[e * 64 + l] = make_float2(a0, a1);
    return;
  }

  const int s = b >> 2, kv = (b >> 1) & 1, hlf = b & 1;
  __shared__ __align__(16) u32 fbS[64][68];
  __shared__ u32 vtS[64][33];
  const float2* nf2 = (const float2*)nf;
  const float2* b22 = (const float2*)b2;

  for (int idx = tid; idx < 4096; idx += 256) {
    int j = idx >> 6, mw = idx & 63;
    float2 f = nf2[((s << 6) + j) * 64 + mw];
    float2 bb = b22[mw];
    fbS[j][mw] = pk(f.x + bb.x, f.y + bb.y);
  }
  __syncthreads();

  uint4 fr[16];
  {
    const uint4* frow = (const uint4*)&fbS[l][0];
    #pragma unroll
    for (int k = 0; k < 16; ++k) fr[k] = frow[k];
  }
  #pragma unroll 1
  for (int p = 0; p < 8; ++p) {
    int c0 = hlf * 64 + cg * 16 + 2 * p;
    int r0 = 128 + kv * 128 + c0;
    const float4* w0 = (const float4*)ipw +
                       (size_t)__builtin_amdgcn_readfirstlane(r0) * 32;
    const float4* w1r = w0 + 32;
    float a0 = ipb[r0], a1 = ipb[r0 + 1];
    #pragma unroll
    for (int k = 0; k < 16; ++k) {
      uint4 F = fr[k];
      float4 wa = w0[2 * k],  wb = w0[2 * k + 1];
      float4 xa = w1r[2 * k], xb = w1r[2 * k + 1];
      float e0 = bl(F.x), e1 = bh(F.x), e2 = bl(F.y), e3 = bh(F.y);
      float e4 = bl(F.z), e5 = bh(F.z), e6 = bl(F.w), e7 = bh(F.w);
      a0 = fmaf(e0, wa.x, a0); a0 = fmaf(e1, wa.y, a0);
      a0 = fmaf(e2, wa.z, a0); a0 = fmaf(e3, wa.w, a0);
      a0 = fmaf(e4, wb.x, a0); a0 = fmaf(e5, wb.y, a0);
      a0 = fmaf(e6, wb.z, a0); a0 = fmaf(e7, wb.w, a0);
      a1 = fmaf(e0, xa.x, a1); a1 = fmaf(e1, xa.y, a1);
      a1 = fmaf(e2, xa.z, a1); a1 = fmaf(e3, xa.w, a1);
      a1 = fmaf(e4, xb.x, a1); a1 = fmaf(e5, xb.y, a1);
      a1 = fmaf(e6, xb.z, a1); a1 = fmaf(e7, xb.w, a1);
    }
    u32 v = pk(a0, a1);
    int cw = hlf * 32 + cg * 8 + p;
    if (kv == 0) KBt[(((s << 6) + cw) << 6) + l] = v;
    else         vtS[l][cg * 8 + p] = v;
  }
  if (kv == 1) {
    __syncthreads();
    int r = tid >> 2, cb = (tid & 3) * 8;
    #pragma unroll
    for (int k = 0; k < 8; ++k)
      VB[(((s << 6) + r) << 6) + hlf * 32 + cb + k] = vtS[r][cb + k];
  }
}

// ---------------- kernel 2: Q=2 queries per wave, wave-synchronous ----------
// grid 1024 x 256: b -> s = b>>3, qt = b&7; wave w -> queries qt*8 + 2w + t.
__global__ __launch_bounds__(256, 4) void ee_main(
    const float* __restrict__ nf, const float* __restrict__ pos,
    const float* __restrict__ w1, const float* __restrict__ b1,
    const float* __restrict__ ipw, const float* __restrict__ ipb,
    const float* __restrict__ ow, const float* __restrict__ ob,
    const float* __restrict__ pw, const float* __restrict__ pb,
    const float* __restrict__ W2KT, const float* __restrict__ W2VT,
    const u32* __restrict__ KBt, const u32* __restrict__ VB,
    float* __restrict__ outp)
{
  __shared__ __align__(16) float pxS[64], pyS[64], w1xS[64], w1yS[64], b1S[64];
  __shared__ __align__(16) float fqS[4][2][132];     // feats  [w][t][c]
  __shared__ __align__(16) float qS [4][2][132];     // q -> ctx
  __shared__ __align__(16) float qwS[4][2][4][68];   // qw [w][t][hd][e]
  __shared__ __align__(16) float atS[4][2][4][68];   // at [w][t][hd][j]
  __shared__ __align__(16) float whS[4][2][4][68];   // wh [w][t][hd][e] -> ao

  const int tid = threadIdx.x;
  const int s = blockIdx.x >> 3, qt = blockIdx.x & 7;
  const int w = tid >> 6, l = tid & 63;
  const int c0 = 2 * l;

  if (tid < 64) {
    float2 p = ((const float2*)pos)[(s << 6) + tid];
    pxS[tid] = p.x; pyS[tid] = p.y;
    float2 wv = ((const float2*)w1)[tid];
    w1xS[tid] = wv.x; w1yS[tid] = wv.y;
    b1S[tid] = b1[tid];
  }
  __syncthreads();
  // ---- no block barriers past here ----

  int il[2], ig[2];
  #pragma unroll
  for (int t = 0; t < 2; ++t) { il[t] = qt * 8 + 2 * w + t; ig[t] = (s << 6) + il[t]; }

  // S1: feats for 2 queries -> LDS
  #pragma unroll
  for (int t = 0; t < 2; ++t)
    *(float2*)&fqS[w][t][c0] = ((const float2*)nf)[ig[t] * 64 + l];
  wsync();

  // S2: q = Wq @ feats + bq  (lane -> channels c0,c0+1; fp32 weights direct)
  {
    float2 bq = ((const float2*)ipb)[l];
    float a0[2] = {bq.x, bq.x}, a1[2] = {bq.y, bq.y};
    const float4* Wa = (const float4*)ipw + (size_t)c0 * 32;
    const float4* Wb = Wa + 32;
    #pragma unroll 4
    for (int m8 = 0; m8 < 16; ++m8) {
      float4 wa0 = Wa[2 * m8], wa1 = Wa[2 * m8 + 1];
      float4 wb0 = Wb[2 * m8], wb1 = Wb[2 * m8 + 1];
      #pragma unroll
      for (int t = 0; t < 2; ++t) {
        float4 f0 = *(const float4*)&fqS[w][t][8 * m8];
        float4 f1 = *(const float4*)&fqS[w][t][8 * m8 + 4];
        a0[t] = dot8f(wa0, wa1, f0, f1, a0[t]);
        a1[t] = dot8f(wb0, wb1, f0, f1, a1[t]);
      }
    }
    #pragma unroll
    for (int t = 0; t < 2; ++t)
      *(float2*)&qS[w][t][c0] = make_float2(a0[t], a1[t]);
  }
  wsync();

  // S4: qw[t][hd][e=l] = q_hd . W2k[:,e]_hd
  {
    const float4* G4 = (const float4*)W2KT;
    #pragma unroll
    for (int hd = 0; hd < 4; ++hd) {
      float acc[2] = {0.f, 0.f};
      #pragma unroll
      for (int dq = 0; dq < 8; ++dq) {
        float4 g = G4[l * 32 + hd * 8 + dq];
        #pragma unroll
        for (int t = 0; t < 2; ++t) {
          float4 qf = *(const float4*)&qS[w][t][hd * 32 + 4 * dq];
          acc[t] = fmaf(g.x, qf.x, acc[t]); acc[t] = fmaf(g.y, qf.y, acc[t]);
          acc[t] = fmaf(g.z, qf.z, acc[t]); acc[t] = fmaf(g.w, qf.w, acc[t]);
        }
      }
      #pragma unroll
      for (int t = 0; t < 2; ++t) qwS[w][t][hd][l] = acc[t];
    }
  }
  wsync();

  // S5: scores + softmax (lane = j)
  float at[2][4];        // [t][hd]
  float pix[2], piy[2];
  {
    float pjx = pxS[l], pjy = pyS[l];
    float rx[2], ry[2];
    #pragma unroll
    for (int t = 0; t < 2; ++t) {
      pix[t] = pxS[il[t]]; piy[t] = pyS[il[t]];      // broadcast reads
      rx[t] = pjx - pix[t]; ry[t] = pjy - piy[t];
    }
    float sc[2][4];
    #pragma unroll
    for (int t = 0; t < 2; ++t)
      #pragma unroll
      for (int hd = 0; hd < 4; ++hd) sc[t][hd] = 0.f;

    const u32* kbp = KBt + (s << 12);
    #pragma unroll 8
    for (int m2 = 0; m2 < 32; ++m2) {
      u32 u0 = kbp[((2 * m2) << 6) + l];
      u32 u1 = kbp[((2 * m2 + 1) << 6) + l];
      const int hd = m2 >> 3;
      #pragma unroll
      for (int t = 0; t < 2; ++t) {
        float4 qf = *(const float4*)&qS[w][t][4 * m2];
        sc[t][hd] = fmaf(bl(u0), qf.x, sc[t][hd]);
        sc[t][hd] = fmaf(bh(u0), qf.y, sc[t][hd]);
        sc[t][hd] = fmaf(bl(u1), qf.z, sc[t][hd]);
        sc[t][hd] = fmaf(bh(u1), qf.w, sc[t][hd]);
      }
    }
    #pragma unroll 2
    for (int eb = 0; eb < 8; ++eb) {
      float4 wx0 = *(const float4*)&w1xS[8 * eb];
      float4 wx1 = *(const float4*)&w1xS[8 * eb + 4];
      float4 wy0 = *(const float4*)&w1yS[8 * eb];
      float4 wy1 = *(const float4*)&w1yS[8 * eb + 4];
      float4 bb0 = *(const float4*)&b1S[8 * eb];
      float4 bb1 = *(const float4*)&b1S[8 * eb + 4];
      #pragma unroll
      for (int t = 0; t < 2; ++t) {
        float h0 = fmaxf(0.f, fmaf(rx[t], wx0.x, fmaf(ry[t], wy0.x, bb0.x)));
        float h1 = fmaxf(0.f, fmaf(rx[t], wx0.y, fmaf(ry[t], wy0.y, bb0.y)));
        float h2 = fmaxf(0.f, fmaf(rx[t], wx0.z, fmaf(ry[t], wy0.z, bb0.z)));
        float h3 = fmaxf(0.f, fmaf(rx[t], wx0.w, fmaf(ry[t], wy0.w, bb0.w)));
        float h4 = fmaxf(0.f, fmaf(rx[t], wx1.x, fmaf(ry[t], wy1.x, bb1.x)));
        float h5 = fmaxf(0.f, fmaf(rx[t], wx1.y, fmaf(ry[t], wy1.y, bb1.y)));
        float h6 = fmaxf(0.f, fmaf(rx[t], wx1.z, fmaf(ry[t], wy1.z, bb1.z)));
        float h7 = fmaxf(0.f, fmaf(rx[t], wx1.w, fmaf(ry[t], wy1.w, bb1.w)));
        #pragma unroll
        for (int hd = 0; hd < 4; ++hd) {
          float4 q0 = *(const float4*)&qwS[w][t][hd][8 * eb];
          float4 q1 = *(const float4*)&qwS[w][t][hd][8 * eb + 4];
          float a = sc[t][hd];
          a = fmaf(q0.x, h0, a); a = fmaf(q0.y, h1, a);
          a = fmaf(q0.z, h2, a); a = fmaf(q0.w, h3, a);
          a = fmaf(q1.x, h4, a); a = fmaf(q1.y, h5, a);
          a = fmaf(q1.z, h6, a); a = fmaf(q1.w, h7, a);
          sc[t][hd] = a;
        }
      }
    }
    #pragma unroll
    for (int t = 0; t < 2; ++t) {
      #pragma unroll
      for (int hd = 0; hd < 4; ++hd) {
        float v = sc[t][hd] * SCALE;
        float m = v;
        #pragma unroll
        for (int off = 32; off > 0; off >>= 1) m = fmaxf(m, __shfl_xor(m, off));
        float p = __expf(v - m);
        float su = p;
        #pragma unroll
        for (int off = 32; off > 0; off >>= 1) su += __shfl_xor(su, off);
#if __has_builtin(__builtin_amdgcn_rcpf)
        at[t][hd] = p * __builtin_amdgcn_rcpf(su);
#else
        at[t][hd] = p / su;
#endif
        atS[w][t][hd][l] = at[t][hd];
      }
    }
  }
  wsync();

  // S6: wh[t][hd][e=l] = sum_j at[t][hd][j]*hid[t][j][e]
  {
    float wx = w1xS[l], wy = w1yS[l], bb = b1S[l];
    float wh[2][4];
    #pragma unroll
    for (int t = 0; t < 2; ++t)
      #pragma unroll
      for (int hd = 0; hd < 4; ++hd) wh[t][hd] = 0.f;
    #pragma unroll 4
    for (int j4 = 0; j4 < 16; ++j4) {
      float4 px = *(const float4*)&pxS[4 * j4];
      float4 py = *(const float4*)&pyS[4 * j4];
      #pragma unroll
      for (int t = 0; t < 2; ++t) {
        float4 a0v = *(const float4*)&atS[w][t][0][4 * j4];
        float4 a1v = *(const float4*)&atS[w][t][1][4 * j4];
        float4 a2v = *(const float4*)&atS[w][t][2][4 * j4];
        float4 a3v = *(const float4*)&atS[w][t][3][4 * j4];
        float h;
        h = fmaxf(0.f, fmaf(px.x - pix[t], wx, fmaf(py.x - piy[t], wy, bb)));
        wh[t][0] = fmaf(a0v.x, h, wh[t][0]); wh[t][1] = fmaf(a1v.x, h, wh[t][1]);
        wh[t][2] = fmaf(a2v.x, h, wh[t][2]); wh[t][3] = fmaf(a3v.x, h, wh[t][3]);
        h = fmaxf(0.f, fmaf(px.y - pix[t], wx, fmaf(py.y - piy[t], wy, bb)));
        wh[t][0] = fmaf(a0v.y, h, wh[t][0]); wh[t][1] = fmaf(a1v.y, h, wh[t][1]);
        wh[t][2] = fmaf(a2v.y, h, wh[t][2]); wh[t][3] = fmaf(a3v.y, h, wh[t][3]);
        h = fmaxf(0.f, fmaf(px.z - pix[t], wx, fmaf(py.z - piy[t], wy, bb)));
        wh[t][0] = fmaf(a0v.z, h, wh[t][0]); wh[t][1] = fmaf(a1v.z, h, wh[t][1]);
        wh[t][2] = fmaf(a2v.z, h, wh[t][2]); wh[t][3] = fmaf(a3v.z, h, wh[t][3]);
        h = fmaxf(0.f, fmaf(px.w - pix[t], wx, fmaf(py.w - piy[t], wy, bb)));
        wh[t][0] = fmaf(a0v.w, h, wh[t][0]); wh[t][1] = fmaf(a1v.w, h, wh[t][1]);
        wh[t][2] = fmaf(a2v.w, h, wh[t][2]); wh[t][3] = fmaf(a3v.w, h, wh[t][3]);
      }
    }
    #pragma unroll
    for (int t = 0; t < 2; ++t)
      #pragma unroll
      for (int hd = 0; hd < 4; ++hd) whS[w][t][hd][l] = wh[t][hd];
  }
  wsync();

  // S7: ctx (lane -> channels c0,c0+1; head = l>>4)
  {
    const int hd = l >> 4;
    float cx0[2] = {0, 0}, cx1[2] = {0, 0};
    const float2* V2 = (const float2*)W2VT;
    const u32* vbp = VB + (s << 12);
    #pragma unroll 4
    for (int n4 = 0; n4 < 16; ++n4) {
      float2 g0 = V2[((4 * n4 + 0) << 6) + l];
      float2 g1 = V2[((4 * n4 + 1) << 6) + l];
      float2 g2 = V2[((4 * n4 + 2) << 6) + l];
      float2 g3 = V2[((4 * n4 + 3) << 6) + l];
      u32 v0 = vbp[((4 * n4 + 0) << 6) + l];
      u32 v1 = vbp[((4 * n4 + 1) << 6) + l];
      u32 v2 = vbp[((4 * n4 + 2) << 6) + l];
      u32 v3 = vbp[((4 * n4 + 3) << 6) + l];
      #pragma unroll
      for (int t = 0; t < 2; ++t) {
        float4 whv = *(const float4*)&whS[w][t][hd][4 * n4];
        float4 atv = *(const float4*)&atS[w][t][hd][4 * n4];
        float a0 = cx0[t], a1 = cx1[t];
        a0 = fmaf(whv.x, g0.x, a0); a1 = fmaf(whv.x, g0.y, a1);
        a0 = fmaf(atv.x, bl(v0), a0); a1 = fmaf(atv.x, bh(v0), a1);
        a0 = fmaf(whv.y, g1.x, a0); a1 = fmaf(whv.y, g1.y, a1);
        a0 = fmaf(atv.y, bl(v1), a0); a1 = fmaf(atv.y, bh(v1), a1);
        a0 = fmaf(whv.z, g2.x, a0); a1 = fmaf(whv.z, g2.y, a1);
        a0 = fmaf(atv.z, bl(v2), a0); a1 = fmaf(atv.z, bh(v2), a1);
        a0 = fmaf(whv.w, g3.x, a0); a1 = fmaf(whv.w, g3.y, a1);
        a0 = fmaf(atv.w, bl(v3), a0); a1 = fmaf(atv.w, bh(v3), a1);
        cx0[t] = a0; cx1[t] = a1;
      }
    }
    wsync();
    #pragma unroll
    for (int t = 0; t < 2; ++t)
      *(float2*)&qS[w][t][c0] = make_float2(cx0[t], cx1[t]);   // ctx over q
  }
  wsync();

  // S8: attn_out = out_w @ ctx + out_b   (fp32 weights direct; -> whS flat)
  {
    float2 b = ((const float2*)ob)[l];
    float a0[2] = {b.x, b.x}, a1[2] = {b.y, b.y};
    const float4* Wa = (const float4*)ow + (size_t)c0 * 32;
    const float4* Wb = Wa + 32;
    #pragma unroll 4
    for (int m8 = 0; m8 < 16; ++m8) {
      float4 wa0 = Wa[2 * m8], wa1 = Wa[2 * m8 + 1];
      float4 wb0 = Wb[2 * m8], wb1 = Wb[2 * m8 + 1];
      #pragma unroll
      for (int t = 0; t < 2; ++t) {
        float4 f0 = *(const float4*)&qS[w][t][8 * m8];
        float4 f1 = *(const float4*)&qS[w][t][8 * m8 + 4];
        a0[t] = dot8f(wa0, wa1, f0, f1, a0[t]);
        a1[t] = dot8f(wb0, wb1, f0, f1, a1[t]);
      }
    }
    wsync();   // whS (wh) reads in S7 complete before overwrite
    #pragma unroll
    for (int t = 0; t < 2; ++t)
      *(float2*)(&whS[w][t][0][0] + c0) = make_float2(a0[t], a1[t]);
  }
  wsync();

  // S9: out = proj_w @ [feats; attn_out] + proj_b  (fp32 weights direct)
  {
    float2 b = ((const float2*)pb)[l];
    float a0[2] = {b.x, b.x}, a1[2] = {b.y, b.y};
    const float4* Pa = (const float4*)pw + (size_t)c0 * 64;
    const float4* Pb = Pa + 64;
    #pragma unroll 2
    for (int m8 = 0; m8 < 16; ++m8) {
      float4 pa0 = Pa[2 * m8],      pa1 = Pa[2 * m8 + 1];
      float4 pa2 = Pa[32 + 2 * m8], pa3 = Pa[33 + 2 * m8];
      float4 pb0 = Pb[2 * m8],      pb1 = Pb[2 * m8 + 1];
      float4 pb2 = Pb[32 + 2 * m8], pb3 = Pb[33 + 2 * m8];
      #pragma unroll
      for (int t = 0; t < 2; ++t) {
        float4 f0 = *(const float4*)&fqS[w][t][8 * m8];
        float4 f1 = *(const float4*)&fqS[w][t][8 * m8 + 4];
        float4 g0 = *(const float4*)(&whS[w][t][0][0] + 8 * m8);
        float4 g1 = *(const float4*)(&whS[w][t][0][0] + 8 * m8 + 4);
        a0[t] = dot8f(pa0, pa1, f0, f1, a0[t]);
        a1[t] = dot8f(pb0, pb1, f0, f1, a1[t]);
        a0[t] = dot8f(pa2, pa3, g0, g1, a0[t]);
        a1[t] = dot8f(pb2, pb3, g0, g1, a1[t]);
      }
    }
    #pragma unroll
    for (int t = 0; t < 2; ++t)
      ((float2*)outp)[ig[t] * 64 + l] = make_float2(a0[t], a1[t]);
  }
}

extern "C" void kernel_launch(void* const* d_in, const int* in_sizes, int n_in,
                              void* d_out, int out_size, void* d_ws, size_t ws_size,
                              hipStream_t stream) {
  (void)in_sizes; (void)n_in; (void)out_size; (void)ws_size;
  const float* nf  = (const float*)d_in[0];
  const float* pos = (const float*)d_in[1];
  const float* w1  = (const float*)d_in[2];
  const float* b1  = (const float*)d_in[3];
  const float* w2  = (const float*)d_in[4];
  const float* b2  = (const float*)d_in[5];
  const float* ipw = (const float*)d_in[6];
  const float* ipb = (const float*)d_in[7];
  const float* ow  = (const float*)d_in[8];
  const float* ob  = (const float*)d_in[9];
  const float* pw  = (const float*)d_in[10];
  const float* pb  = (const float*)d_in[11];

  char* ws = (char*)d_ws;
  float* W2KT = (float*)(ws);
  float* W2VT = (float*)(ws + (32 << 10));
  u32* KBt  = (u32*)(ws + (64 << 10));
  u32* VB   = (u32*)(ws + (64 << 10) + (128 * 4096 * 4));

  ee_setup<<<dim3(544), dim3(256), 0, stream>>>(nf, b2, ipw, ipb, w2,
                                                W2KT, W2VT, KBt, VB);
  ee_main<<<dim3(1024), dim3(256), 0, stream>>>(nf, pos, w1, b1, ipw, ipb,
                                                ob ? ow : ow, ob, pw, pb,
                                                W2KT, W2VT, KBt, VB, (float*)d_out);
}

// Round 2
// 183.618 us; speedup vs baseline: 1.3782x; 1.3782x over previous
//
#include <hip/hip_runtime.h>
#include <hip/hip_bf16.h>

// EdgeEncoder — fp32 inputs, algebraically folded attention:
//   k[i,j] = kbase[j] + W2k @ hid[i,j],   W2k = Wk @ W2
//   score  = q.kbase[j] + qw[i,hd].hid[i,j]
//   ctx    = sum_j attn*vbase[j] + W2v @ (sum_j attn*hid[i,j])
//
// R9 = R7 revert + LDS alias. R8 post-mortem: fp32 direct weights 4x'd the
// per-query weight-load count (128 float4/query vs 32 uint4/query) and Q=2
// halved ILP -> vmcnt-stall-bound (VALUBusy 24%). Reverted to Q=4 + bf16
// packed weights (proven 86us). New lever: qwS (dead after S5) and whS
// (born in S6) are [w]-private and wave-program-order separated -> alias
// into one buffer qwhS. LDS 70.4KB -> 53.0KB -> 3 blocks/CU (was 2),
// 3 waves/SIMD, +50% latency hiding with an identical instruction stream.
//
// ws layout (bytes):
//   [0,32K)     W2KT fp32 [e][ch]
//   [32K,64K)   W2VT fp32 [e][ch]
//   [64K,96K)   WQB  u32  [c][mw]   Wq bf16-pairs
//   [96K,128K)  OWB  u32  [c][mw]   out_w
//   [128K,192K) PWB  u32  [c][mw]   proj_w
//   [192K,+2M)  KBt  u32  [s][cw][j]  kbase bf16-pairs, j fastest
//   [+2M,+4M)   VB   u32  [s][j][cw]  vbase, cw fastest

typedef unsigned int u32;
#define SCALE 0.17677669529663689f   // 1/sqrt(32)

__device__ __forceinline__ float bl(u32 u){ union{u32 x; float f;} c; c.x = u << 16; return c.f; }
__device__ __forceinline__ float bh(u32 u){ union{u32 x; float f;} c; c.x = u & 0xffff0000u; return c.f; }
__device__ __forceinline__ u32 pk(float a, float b){
  union{float f; u32 x;} ca, cb; ca.f = a; cb.f = b;
  u32 ua = (ca.x + 0x7fffu + ((ca.x >> 16) & 1u)) >> 16;   // RNE fp32->bf16
  u32 ub = (cb.x + 0x7fffu + ((cb.x >> 16) & 1u)) >> 16;
  return ua | (ub << 16);
}
__device__ __forceinline__ float dot8(uint4 u, float4 f0, float4 f1, float acc){
  acc = fmaf(bl(u.x), f0.x, acc); acc = fmaf(bh(u.x), f0.y, acc);
  acc = fmaf(bl(u.y), f0.z, acc); acc = fmaf(bh(u.y), f0.w, acc);
  acc = fmaf(bl(u.z), f1.x, acc); acc = fmaf(bh(u.z), f1.y, acc);
  acc = fmaf(bl(u.w), f1.z, acc); acc = fmaf(bh(u.w), f1.w, acc);
  return acc;
}
__device__ __forceinline__ void wsync(){
  __builtin_amdgcn_s_waitcnt(0xC07F);   // lgkmcnt(0)
  __builtin_amdgcn_wave_barrier();
}

// ---------------- kernel 1: setup (R5-proven) -------------------------------
__global__ __launch_bounds__(256, 2) void ee_setup(
    const float* __restrict__ nf, const float* __restrict__ b2,
    const float* __restrict__ ipw, const float* __restrict__ ipb,
    const float* __restrict__ w2,
    const float* __restrict__ ow, const float* __restrict__ pw,
    float* __restrict__ W2KT, float* __restrict__ W2VT,
    u32* __restrict__ WQB, u32* __restrict__ OWB, u32* __restrict__ PWB,
    u32* __restrict__ KBt, u32* __restrict__ VB)
{
  const int tid = threadIdx.x, b = blockIdx.x;
  const int cg = tid >> 6, l = tid & 63;
  const float2* ipw2 = (const float2*)ipw;
  const float2* ow2  = (const float2*)ow;
  const float2* pw2  = (const float2*)pw;

  if (b >= 544) {              // ---- weight packing, fully coalesced ----
    for (int k = 0; k < 16; ++k) {
      int i = (b - 544) * 4096 + k * 256 + tid;    // 0..32767
      if (i < 8192)       { float2 f = ipw2[i];        WQB[i]        = pk(f.x, f.y); }
      else if (i < 16384) { float2 f = ow2[i - 8192];  OWB[i - 8192] = pk(f.x, f.y); }
      else                { float2 f = pw2[i - 16384]; PWB[i - 16384]= pk(f.x, f.y); }
    }
    return;
  }
  if (b >= 512) {              // ---- W2 folds: W2x[ch][e] = Wk/Wv @ W2 ----
    int t = (b - 512) * 4 + cg;
    int kv = t & 1, e = t >> 1;
    int c0 = 2 * l;
    const float4* rp = (const float4*)ipw + (size_t)(128 + kv * 128 + c0) * 32;
    const float* w2e = w2 + __builtin_amdgcn_readfirstlane(e);
    float a0 = 0.f, a1 = 0.f;
    #pragma unroll 8
    for (int c4 = 0; c4 < 32; ++c4) {
      float4 wa = rp[c4], wb = rp[32 + c4];
      float x0 = w2e[(4 * c4 + 0) * 64];
      float x1 = w2e[(4 * c4 + 1) * 64];
      float x2 = w2e[(4 * c4 + 2) * 64];
      float x3 = w2e[(4 * c4 + 3) * 64];
      a0 = fmaf(wa.x, x0, a0); a0 = fmaf(wa.y, x1, a0);
      a0 = fmaf(wa.z, x2, a0); a0 = fmaf(wa.w, x3, a0);
      a1 = fmaf(wb.x, x0, a1); a1 = fmaf(wb.y, x1, a1);
      a1 = fmaf(wb.z, x2, a1); a1 = fmaf(wb.w, x3, a1);
    }
    float* dst = kv ? W2VT : W2KT;
    ((float2*)dst)[e * 64 + l] = make_float2(a0, a1);
    return;
  }

  const int s = b >> 2, kv = (b >> 1) & 1, hlf = b & 1;
  __shared__ __align__(16) u32 fbS[64][68];
  __shared__ u32 vtS[64][33];
  const float2* nf2 = (const float2*)nf;
  const float2* b22 = (const float2*)b2;

  for (int idx = tid; idx < 4096; idx += 256) {
    int j = idx >> 6, mw = idx & 63;
    float2 f = nf2[((s << 6) + j) * 64 + mw];
    float2 bb = b22[mw];
    fbS[j][mw] = pk(f.x + bb.x, f.y + bb.y);
  }
  __syncthreads();

  uint4 fr[16];
  {
    const uint4* frow = (const uint4*)&fbS[l][0];
    #pragma unroll
    for (int k = 0; k < 16; ++k) fr[k] = frow[k];
  }
  #pragma unroll 1
  for (int p = 0; p < 8; ++p) {
    int c0 = hlf * 64 + cg * 16 + 2 * p;
    int r0 = 128 + kv * 128 + c0;
    const float4* w0 = (const float4*)ipw +
                       (size_t)__builtin_amdgcn_readfirstlane(r0) * 32;
    const float4* w1r = w0 + 32;
    float a0 = ipb[r0], a1 = ipb[r0 + 1];
    #pragma unroll
    for (int k = 0; k < 16; ++k) {
      uint4 F = fr[k];
      float4 wa = w0[2 * k],  wb = w0[2 * k + 1];
      float4 xa = w1r[2 * k], xb = w1r[2 * k + 1];
      float e0 = bl(F.x), e1 = bh(F.x), e2 = bl(F.y), e3 = bh(F.y);
      float e4 = bl(F.z), e5 = bh(F.z), e6 = bl(F.w), e7 = bh(F.w);
      a0 = fmaf(e0, wa.x, a0); a0 = fmaf(e1, wa.y, a0);
      a0 = fmaf(e2, wa.z, a0); a0 = fmaf(e3, wa.w, a0);
      a0 = fmaf(e4, wb.x, a0); a0 = fmaf(e5, wb.y, a0);
      a0 = fmaf(e6, wb.z, a0); a0 = fmaf(e7, wb.w, a0);
      a1 = fmaf(e0, xa.x, a1); a1 = fmaf(e1, xa.y, a1);
      a1 = fmaf(e2, xa.z, a1); a1 = fmaf(e3, xa.w, a1);
      a1 = fmaf(e4, xb.x, a1); a1 = fmaf(e5, xb.y, a1);
      a1 = fmaf(e6, xb.z, a1); a1 = fmaf(e7, xb.w, a1);
    }
    u32 v = pk(a0, a1);
    int cw = hlf * 32 + cg * 8 + p;
    if (kv == 0) KBt[(((s << 6) + cw) << 6) + l] = v;
    else         vtS[l][cg * 8 + p] = v;
  }
  if (kv == 1) {
    __syncthreads();
    int r = tid >> 2, cb = (tid & 3) * 8;
    #pragma unroll
    for (int k = 0; k < 8; ++k)
      VB[(((s << 6) + r) << 6) + hlf * 32 + cb + k] = vtS[r][cb + k];
  }
}

// ---------------- kernel 2: Q=4 queries per wave, wave-synchronous ----------
// grid 512 x 256: b -> s = b>>2, qt = b&3; wave w -> queries qt*16+4w+t.
// qwhS aliases qw (S4/S5) with wh (S6/S7) and attn_out (S8/S9): both are
// [w]-private and separated by wave program order + wsync -> LDS 53KB,
// 3 blocks/CU.
__global__ __launch_bounds__(256, 3) void ee_main(
    const float* __restrict__ nf, const float* __restrict__ pos,
    const float* __restrict__ w1, const float* __restrict__ b1,
    const float* __restrict__ ipb,
    const float* __restrict__ ob, const float* __restrict__ pb,
    const float* __restrict__ W2KT, const float* __restrict__ W2VT,
    const u32* __restrict__ WQB, const u32* __restrict__ OWB,
    const u32* __restrict__ PWB,
    const u32* __restrict__ KBt, const u32* __restrict__ VB,
    float* __restrict__ outp)
{
  __shared__ __align__(16) float pxS[64], pyS[64], w1xS[64], w1yS[64], b1S[64];
  __shared__ __align__(16) float fqS[4][4][132];     // feats  [w][t][c]
  __shared__ __align__(16) float qS [4][4][132];     // q -> ctx
  __shared__ __align__(16) float qwhS[4][4][4][68];  // qw (S4/S5) | wh/ao (S6+)
  __shared__ __align__(16) float atS[4][4][4][68];   // at [w][t][hd][j]

  const int tid = threadIdx.x;
  const int s = blockIdx.x >> 2, qt = blockIdx.x & 3;
  const int w = tid >> 6, l = tid & 63;
  const int c0 = 2 * l;

  if (tid < 64) {
    float2 p = ((const float2*)pos)[(s << 6) + tid];
    pxS[tid] = p.x; pyS[tid] = p.y;
    float2 wv = ((const float2*)w1)[tid];
    w1xS[tid] = wv.x; w1yS[tid] = wv.y;
    b1S[tid] = b1[tid];
  }
  __syncthreads();
  // ---- no block barriers past here ----

  int il[4], ig[4];
  #pragma unroll
  for (int t = 0; t < 4; ++t) { il[t] = qt * 16 + 4 * w + t; ig[t] = (s << 6) + il[t]; }

  // S1: feats for 4 queries -> LDS
  #pragma unroll
  for (int t = 0; t < 4; ++t)
    *(float2*)&fqS[w][t][c0] = ((const float2*)nf)[ig[t] * 64 + l];
  wsync();

  // S2: q = Wq @ feats + bq  (lane -> channels c0,c0+1; weights reused x4)
  {
    float2 bq = ((const float2*)ipb)[l];
    float a0[4], a1[4];
    #pragma unroll
    for (int t = 0; t < 4; ++t) { a0[t] = bq.x; a1[t] = bq.y; }
    const uint4* W4 = (const uint4*)WQB;
    #pragma unroll 4
    for (int m8 = 0; m8 < 16; ++m8) {
      uint4 ua = W4[c0 * 16 + m8];
      uint4 ub = W4[(c0 + 1) * 16 + m8];
      #pragma unroll
      for (int t = 0; t < 4; ++t) {
        float4 f0 = *(const float4*)&fqS[w][t][8 * m8];
        float4 f1 = *(const float4*)&fqS[w][t][8 * m8 + 4];
        a0[t] = dot8(ua, f0, f1, a0[t]);
        a1[t] = dot8(ub, f0, f1, a1[t]);
      }
    }
    #pragma unroll
    for (int t = 0; t < 4; ++t)
      *(float2*)&qS[w][t][c0] = make_float2(a0[t], a1[t]);
  }
  wsync();

  // S4: qw[t][hd][e=l] = q_hd . W2k[:,e]_hd  (W2KT rows reused x4)
  {
    const float4* G4 = (const float4*)W2KT;
    #pragma unroll
    for (int hd = 0; hd < 4; ++hd) {
      float acc[4] = {0.f, 0.f, 0.f, 0.f};
      #pragma unroll
      for (int dq = 0; dq < 8; ++dq) {
        float4 g = G4[l * 32 + hd * 8 + dq];
        #pragma unroll
        for (int t = 0; t < 4; ++t) {
          float4 qf = *(const float4*)&qS[w][t][hd * 32 + 4 * dq];
          acc[t] = fmaf(g.x, qf.x, acc[t]); acc[t] = fmaf(g.y, qf.y, acc[t]);
          acc[t] = fmaf(g.z, qf.z, acc[t]); acc[t] = fmaf(g.w, qf.w, acc[t]);
        }
      }
      #pragma unroll
      for (int t = 0; t < 4; ++t) qwhS[w][t][hd][l] = acc[t];
    }
  }
  wsync();

  // S5: scores + softmax (lane = j; kb loads reused x4)
  float at[4][4];        // [t][hd]
  float pix[4], piy[4];
  {
    float pjx = pxS[l], pjy = pyS[l];
    float rx[4], ry[4];
    #pragma unroll
    for (int t = 0; t < 4; ++t) {
      pix[t] = pxS[il[t]]; piy[t] = pyS[il[t]];      // broadcast reads
      rx[t] = pjx - pix[t]; ry[t] = pjy - piy[t];
    }
    float sc[4][4];
    #pragma unroll
    for (int t = 0; t < 4; ++t)
      #pragma unroll
      for (int hd = 0; hd < 4; ++hd) sc[t][hd] = 0.f;

    const u32* kbp = KBt + (s << 12);
    #pragma unroll 8
    for (int m2 = 0; m2 < 32; ++m2) {
      u32 u0 = kbp[((2 * m2) << 6) + l];
      u32 u1 = kbp[((2 * m2 + 1) << 6) + l];
      const int hd = m2 >> 3;
      #pragma unroll
      for (int t = 0; t < 4; ++t) {
        float4 qf = *(const float4*)&qS[w][t][4 * m2];
        sc[t][hd] = fmaf(bl(u0), qf.x, sc[t][hd]);
        sc[t][hd] = fmaf(bh(u0), qf.y, sc[t][hd]);
        sc[t][hd] = fmaf(bl(u1), qf.z, sc[t][hd]);
        sc[t][hd] = fmaf(bh(u1), qf.w, sc[t][hd]);
      }
    }
    #pragma unroll 2
    for (int eb = 0; eb < 8; ++eb) {
      float4 wx0 = *(const float4*)&w1xS[8 * eb];
      float4 wx1 = *(const float4*)&w1xS[8 * eb + 4];
      float4 wy0 = *(const float4*)&w1yS[8 * eb];
      float4 wy1 = *(const float4*)&w1yS[8 * eb + 4];
      float4 bb0 = *(const float4*)&b1S[8 * eb];
      float4 bb1 = *(const float4*)&b1S[8 * eb + 4];
      #pragma unroll
      for (int t = 0; t < 4; ++t) {
        float h0 = fmaxf(0.f, fmaf(rx[t], wx0.x, fmaf(ry[t], wy0.x, bb0.x)));
        float h1 = fmaxf(0.f, fmaf(rx[t], wx0.y, fmaf(ry[t], wy0.y, bb0.y)));
        float h2 = fmaxf(0.f, fmaf(rx[t], wx0.z, fmaf(ry[t], wy0.z, bb0.z)));
        float h3 = fmaxf(0.f, fmaf(rx[t], wx0.w, fmaf(ry[t], wy0.w, bb0.w)));
        float h4 = fmaxf(0.f, fmaf(rx[t], wx1.x, fmaf(ry[t], wy1.x, bb1.x)));
        float h5 = fmaxf(0.f, fmaf(rx[t], wx1.y, fmaf(ry[t], wy1.y, bb1.y)));
        float h6 = fmaxf(0.f, fmaf(rx[t], wx1.z, fmaf(ry[t], wy1.z, bb1.z)));
        float h7 = fmaxf(0.f, fmaf(rx[t], wx1.w, fmaf(ry[t], wy1.w, bb1.w)));
        #pragma unroll
        for (int hd = 0; hd < 4; ++hd) {
          float4 q0 = *(const float4*)&qwhS[w][t][hd][8 * eb];
          float4 q1 = *(const float4*)&qwhS[w][t][hd][8 * eb + 4];
          float a = sc[t][hd];
          a = fmaf(q0.x, h0, a); a = fmaf(q0.y, h1, a);
          a = fmaf(q0.z, h2, a); a = fmaf(q0.w, h3, a);
          a = fmaf(q1.x, h4, a); a = fmaf(q1.y, h5, a);
          a = fmaf(q1.z, h6, a); a = fmaf(q1.w, h7, a);
          sc[t][hd] = a;
        }
      }
    }
    #pragma unroll
    for (int t = 0; t < 4; ++t) {
      #pragma unroll
      for (int hd = 0; hd < 4; ++hd) {
        float v = sc[t][hd] * SCALE;
        float m = v;
        #pragma unroll
        for (int off = 32; off > 0; off >>= 1) m = fmaxf(m, __shfl_xor(m, off));
        float p = __expf(v - m);
        float su = p;
        #pragma unroll
        for (int off = 32; off > 0; off >>= 1) su += __shfl_xor(su, off);
#if __has_builtin(__builtin_amdgcn_rcpf)
        at[t][hd] = p * __builtin_amdgcn_rcpf(su);
#else
        at[t][hd] = p / su;
#endif
        atS[w][t][hd][l] = at[t][hd];
      }
    }
  }
  wsync();

  // S6: wh[t][hd][e=l] = sum_j at[t][hd][j]*hid[t][j][e]  (-> qwhS, qw dead)
  {
    float wx = w1xS[l], wy = w1yS[l], bb = b1S[l];
    float wh[4][4];
    #pragma unroll
    for (int t = 0; t < 4; ++t)
      #pragma unroll
      for (int hd = 0; hd < 4; ++hd) wh[t][hd] = 0.f;
    #pragma unroll 4
    for (int j4 = 0; j4 < 16; ++j4) {
      float4 px = *(const float4*)&pxS[4 * j4];
      float4 py = *(const float4*)&pyS[4 * j4];
      #pragma unroll
      for (int t = 0; t < 4; ++t) {
        float4 a0v = *(const float4*)&atS[w][t][0][4 * j4];
        float4 a1v = *(const float4*)&atS[w][t][1][4 * j4];
        float4 a2v = *(const float4*)&atS[w][t][2][4 * j4];
        float4 a3v = *(const float4*)&atS[w][t][3][4 * j4];
        float h;
        h = fmaxf(0.f, fmaf(px.x - pix[t], wx, fmaf(py.x - piy[t], wy, bb)));
        wh[t][0] = fmaf(a0v.x, h, wh[t][0]); wh[t][1] = fmaf(a1v.x, h, wh[t][1]);
        wh[t][2] = fmaf(a2v.x, h, wh[t][2]); wh[t][3] = fmaf(a3v.x, h, wh[t][3]);
        h = fmaxf(0.f, fmaf(px.y - pix[t], wx, fmaf(py.y - piy[t], wy, bb)));
        wh[t][0] = fmaf(a0v.y, h, wh[t][0]); wh[t][1] = fmaf(a1v.y, h, wh[t][1]);
        wh[t][2] = fmaf(a2v.y, h, wh[t][2]); wh[t][3] = fmaf(a3v.y, h, wh[t][3]);
        h = fmaxf(0.f, fmaf(px.z - pix[t], wx, fmaf(py.z - piy[t], wy, bb)));
        wh[t][0] = fmaf(a0v.z, h, wh[t][0]); wh[t][1] = fmaf(a1v.z, h, wh[t][1]);
        wh[t][2] = fmaf(a2v.z, h, wh[t][2]); wh[t][3] = fmaf(a3v.z, h, wh[t][3]);
        h = fmaxf(0.f, fmaf(px.w - pix[t], wx, fmaf(py.w - piy[t], wy, bb)));
        wh[t][0] = fmaf(a0v.w, h, wh[t][0]); wh[t][1] = fmaf(a1v.w, h, wh[t][1]);
        wh[t][2] = fmaf(a2v.w, h, wh[t][2]); wh[t][3] = fmaf(a3v.w, h, wh[t][3]);
      }
    }
    #pragma unroll
    for (int t = 0; t < 4; ++t)
      #pragma unroll
      for (int hd = 0; hd < 4; ++hd) qwhS[w][t][hd][l] = wh[t][hd];
  }
  wsync();

  // S7: ctx (lane -> channels c0,c0+1; head = l>>4); vb/W2VT reused x4
  {
    const int hd = l >> 4;
    float cx0[4] = {0,0,0,0}, cx1[4] = {0,0,0,0};
    const float2* V2 = (const float2*)W2VT;
    const u32* vbp = VB + (s << 12);
    #pragma unroll 4
    for (int n4 = 0; n4 < 16; ++n4) {
      float2 g0 = V2[((4 * n4 + 0) << 6) + l];
      float2 g1 = V2[((4 * n4 + 1) << 6) + l];
      float2 g2 = V2[((4 * n4 + 2) << 6) + l];
      float2 g3 = V2[((4 * n4 + 3) << 6) + l];
      u32 v0 = vbp[((4 * n4 + 0) << 6) + l];
      u32 v1 = vbp[((4 * n4 + 1) << 6) + l];
      u32 v2 = vbp[((4 * n4 + 2) << 6) + l];
      u32 v3 = vbp[((4 * n4 + 3) << 6) + l];
      #pragma unroll
      for (int t = 0; t < 4; ++t) {
        float4 whv = *(const float4*)&qwhS[w][t][hd][4 * n4];
        float4 atv = *(const float4*)&atS[w][t][hd][4 * n4];
        float a0 = cx0[t], a1 = cx1[t];
        a0 = fmaf(whv.x, g0.x, a0); a1 = fmaf(whv.x, g0.y, a1);
        a0 = fmaf(atv.x, bl(v0), a0); a1 = fmaf(atv.x, bh(v0), a1);
        a0 = fmaf(whv.y, g1.x, a0); a1 = fmaf(whv.y, g1.y, a1);
        a0 = fmaf(atv.y, bl(v1), a0); a1 = fmaf(atv.y, bh(v1), a1);
        a0 = fmaf(whv.z, g2.x, a0); a1 = fmaf(whv.z, g2.y, a1);
        a0 = fmaf(atv.z, bl(v2), a0); a1 = fmaf(atv.z, bh(v2), a1);
        a0 = fmaf(whv.w, g3.x, a0); a1 = fmaf(whv.w, g3.y, a1);
        a0 = fmaf(atv.w, bl(v3), a0); a1 = fmaf(atv.w, bh(v3), a1);
        cx0[t] = a0; cx1[t] = a1;
      }
    }
    wsync();
    #pragma unroll
    for (int t = 0; t < 4; ++t)
      *(float2*)&qS[w][t][c0] = make_float2(cx0[t], cx1[t]);   // ctx over q
  }
  wsync();

  // S8: attn_out = out_w @ ctx + out_b   (-> qwhS region, flat per t)
  {
    float2 b = ((const float2*)ob)[l];
    float a0[4], a1[4];
    #pragma unroll
    for (int t = 0; t < 4; ++t) { a0[t] = b.x; a1[t] = b.y; }
    const uint4* W4 = (const uint4*)OWB;
    #pragma unroll 4
    for (int m8 = 0; m8 < 16; ++m8) {
      uint4 ua = W4[c0 * 16 + m8];
      uint4 ub = W4[(c0 + 1) * 16 + m8];
      #pragma unroll
      for (int t = 0; t < 4; ++t) {
        float4 f0 = *(const float4*)&qS[w][t][8 * m8];
        float4 f1 = *(const float4*)&qS[w][t][8 * m8 + 4];
        a0[t] = dot8(ua, f0, f1, a0[t]);
        a1[t] = dot8(ub, f0, f1, a1[t]);
      }
    }
    wsync();   // qwhS (wh) reads in S7 complete before overwrite
    #pragma unroll
    for (int t = 0; t < 4; ++t)
      *(float2*)(&qwhS[w][t][0][0] + c0) = make_float2(a0[t], a1[t]);
  }
  wsync();

  // S9: out = proj_w @ [feats; attn_out] + proj_b  (fp32 out)
  {
    float2 b = ((const float2*)pb)[l];
    float a0[4], a1[4];
    #pragma unroll
    for (int t = 0; t < 4; ++t) { a0[t] = b.x; a1[t] = b.y; }
    const uint4* W4 = (const uint4*)PWB;
    #pragma unroll 2
    for (int m8 = 0; m8 < 16; ++m8) {
      uint4 ua = W4[c0 * 32 + m8];
      uint4 ub = W4[(c0 + 1) * 32 + m8];
      uint4 uc = W4[c0 * 32 + 16 + m8];
      uint4 ud = W4[(c0 + 1) * 32 + 16 + m8];
      #pragma unroll
      for (int t = 0; t < 4; ++t) {
        float4 f0 = *(const float4*)&fqS[w][t][8 * m8];
        float4 f1 = *(const float4*)&fqS[w][t][8 * m8 + 4];
        float4 g0 = *(const float4*)(&qwhS[w][t][0][0] + 8 * m8);
        float4 g1 = *(const float4*)(&qwhS[w][t][0][0] + 8 * m8 + 4);
        a0[t] = dot8(ua, f0, f1, a0[t]);
        a1[t] = dot8(ub, f0, f1, a1[t]);
        a0[t] = dot8(uc, g0, g1, a0[t]);
        a1[t] = dot8(ud, g0, g1, a1[t]);
      }
    }
    #pragma unroll
    for (int t = 0; t < 4; ++t)
      ((float2*)outp)[ig[t] * 64 + l] = make_float2(a0[t], a1[t]);
  }
}

extern "C" void kernel_launch(void* const* d_in, const int* in_sizes, int n_in,
                              void* d_out, int out_size, void* d_ws, size_t ws_size,
                              hipStream_t stream) {
  (void)in_sizes; (void)n_in; (void)out_size; (void)ws_size;
  const float* nf  = (const float*)d_in[0];
  const float* pos = (const float*)d_in[1];
  const float* w1  = (const float*)d_in[2];
  const float* b1  = (const float*)d_in[3];
  const float* w2  = (const float*)d_in[4];
  const float* b2  = (const float*)d_in[5];
  const float* ipw = (const float*)d_in[6];
  const float* ipb = (const float*)d_in[7];
  const float* ow  = (const float*)d_in[8];
  const float* ob  = (const float*)d_in[9];
  const float* pw  = (const float*)d_in[10];
  const float* pb  = (const float*)d_in[11];

  char* ws = (char*)d_ws;
  float* W2KT = (float*)(ws);
  float* W2VT = (float*)(ws + (32 << 10));
  u32* WQB  = (u32*)(ws + (64 << 10));
  u32* OWB  = (u32*)(ws + (96 << 10));
  u32* PWB  = (u32*)(ws + (128 << 10));
  u32* KBt  = (u32*)(ws + (192 << 10));
  u32* VB   = (u32*)(ws + (192 << 10) + (128 * 4096 * 4));

  ee_setup<<<dim3(552), dim3(256), 0, stream>>>(nf, b2, ipw, ipb, w2, ow, pw,
                                                W2KT, W2VT, WQB, OWB, PWB, KBt, VB);
  ee_main<<<dim3(512), dim3(256), 0, stream>>>(nf, pos, w1, b1, ipb, ob, pb,
                                               W2KT, W2VT, WQB, OWB, PWB,
                                               KBt, VB, (float*)d_out);
}